// Round 1
// baseline (283.366 us; speedup 1.0000x reference)
//
#include <hip/hip_runtime.h>
#include <stdint.h>

#define B_ 4
#define L_ 4096
#define D_ 1024
#define C_ 2048
#define M_ (B_ * L_)  // 16384

typedef __attribute__((ext_vector_type(8))) short s16x8;
typedef __attribute__((ext_vector_type(4))) float fx4;
typedef unsigned short bfu;  // bf16 bits

__device__ __forceinline__ float bits2f(short s) {
  return __uint_as_float(((uint32_t)(unsigned short)s) << 16);
}
__device__ __forceinline__ bfu f2bf(float f) {
  uint32_t u = __float_as_uint(f);
  uint32_t r = (u + 0x7FFFu + ((u >> 16) & 1u)) >> 16;  // RNE
  return (bfu)r;
}

__device__ __forceinline__ void gload_lds16(const void* g, void* l) {
  __builtin_amdgcn_global_load_lds(
      (const __attribute__((address_space(1))) void*)g,
      (__attribute__((address_space(3))) void*)l, 16, 0, 0);
}

// ---------------- transpose + fp32->bf16 convert: out[c][r] = in[r][c] ----------------
template <int R, int CC>
__global__ __launch_bounds__(256) void transpose_cvt(const float* __restrict__ in,
                                                     bfu* __restrict__ out) {
  __shared__ float tile[32][33];
  const int bx = blockIdx.x;  // tile along CC
  const int by = blockIdx.y;  // tile along R
  const int tx = threadIdx.x;
  for (int j = threadIdx.y; j < 32; j += 8)
    tile[j][tx] = in[(size_t)(by * 32 + j) * CC + bx * 32 + tx];
  __syncthreads();
  for (int j = threadIdx.y; j < 32; j += 8)
    out[(size_t)(bx * 32 + j) * R + by * 32 + tx] = f2bf(tile[tx][j]);
}

// ---------------- 128x128 tile GEMM, BK=32, 4 waves (2x2), 16x16x32 bf16 MFMA ----------
// A: [M][KD] (fp32 if A_F32 else bf16-bits). Bt: [N][KD] bf16-bits (B transposed).
// C = A*B + bias; out bf16-bits or fp32.
template <int N, int KD, bool A_F32, bool OUT_BF16>
__global__ __launch_bounds__(256) void gemm_tile(const void* __restrict__ Aptr,
                                                 const bfu* __restrict__ Bt,
                                                 const float* __restrict__ bias,
                                                 void* __restrict__ Cptr) {
  __shared__ bfu sA[128 * 32];
  __shared__ bfu sB[128 * 32];
  const int t = threadIdx.x;
  const int lane = t & 63, wid = t >> 6;
  const int wr = wid >> 1, wc = wid & 1;   // 2x2 wave grid, each wave 64x64
  const int lr = lane & 15, lg = lane >> 4;
  const int row0 = blockIdx.x * 128, col0 = blockIdx.y * 128;
  const int sr = t >> 2;            // staging row 0..63 (half-tile)
  const int sk = (t & 3) * 8;       // staging k offset
  fx4 acc[4][4] = {};

  for (int k0 = 0; k0 < KD; k0 += 32) {
    if constexpr (A_F32) {
      const float* A = (const float*)Aptr;
      const float* p0 = A + (size_t)(row0 + sr) * KD + k0 + sk;
      const float* p1 = p0 + (size_t)64 * KD;
      fx4 a0 = *(const fx4*)p0, a1 = *(const fx4*)(p0 + 4);
      fx4 a2 = *(const fx4*)p1, a3 = *(const fx4*)(p1 + 4);
      s16x8 u0, u1;
#pragma unroll
      for (int i = 0; i < 4; i++) {
        u0[i] = (short)f2bf(a0[i]);
        u0[i + 4] = (short)f2bf(a1[i]);
        u1[i] = (short)f2bf(a2[i]);
        u1[i + 4] = (short)f2bf(a3[i]);
      }
      *reinterpret_cast<s16x8*>(&sA[t * 8]) = u0;
      *reinterpret_cast<s16x8*>(&sA[2048 + t * 8]) = u1;
    } else {
      const bfu* A = (const bfu*)Aptr;
      gload_lds16(A + (size_t)(row0 + sr) * KD + k0 + sk, &sA[t * 8]);
      gload_lds16(A + (size_t)(row0 + 64 + sr) * KD + k0 + sk, &sA[2048 + t * 8]);
    }
    gload_lds16(Bt + (size_t)(col0 + sr) * KD + k0 + sk, &sB[t * 8]);
    gload_lds16(Bt + (size_t)(col0 + 64 + sr) * KD + k0 + sk, &sB[2048 + t * 8]);
    __syncthreads();

    s16x8 af[4], bfr[4];
#pragma unroll
    for (int i = 0; i < 4; i++) {
      af[i] = *reinterpret_cast<const s16x8*>(&sA[(wr * 64 + i * 16 + lr) * 32 + lg * 8]);
      bfr[i] = *reinterpret_cast<const s16x8*>(&sB[(wc * 64 + i * 16 + lr) * 32 + lg * 8]);
    }
#pragma unroll
    for (int i = 0; i < 4; i++)
#pragma unroll
      for (int j = 0; j < 4; j++)
        acc[i][j] =
            __builtin_amdgcn_mfma_f32_16x16x32_bf16(af[i], bfr[j], acc[i][j], 0, 0, 0);
    __syncthreads();
  }

  // epilogue: C/D layout col=lane&15, row=(lane>>4)*4+reg  [measured m89/m91]
#pragma unroll
  for (int i = 0; i < 4; i++)
#pragma unroll
    for (int j = 0; j < 4; j++)
#pragma unroll
      for (int r = 0; r < 4; r++) {
        const int row = row0 + wr * 64 + i * 16 + lg * 4 + r;
        const int col = col0 + wc * 64 + j * 16 + lr;
        const float v = acc[i][j][r] + bias[col];
        if constexpr (OUT_BF16)
          ((bfu*)Cptr)[(size_t)row * N + col] = f2bf(v);
        else
          ((float*)Cptr)[(size_t)row * N + col] = v;
      }
}

// ---------------- depthwise causal conv, K=4, over xe [M][C] bf16 -> y [M][C] bf16 ------
__global__ __launch_bounds__(256) void dwconv_kernel(const bfu* __restrict__ xe,
                                                     const float* __restrict__ cw,
                                                     const float* __restrict__ cb,
                                                     bfu* __restrict__ y) {
  const int m = blockIdx.x;            // one block per (b,l) row; 256 threads cover C
  const int cg = threadIdx.x << 3;     // 8 channels per thread
  const int l = m & (L_ - 1);
  float acc[8];
  fx4 c0 = *(const fx4*)(cb + cg), c1 = *(const fx4*)(cb + cg + 4);
#pragma unroll
  for (int i = 0; i < 4; i++) {
    acc[i] = c0[i];
    acc[i + 4] = c1[i];
  }
#pragma unroll
  for (int tt = 0; tt < 4; tt++) {
    const int lm = l - 3 + tt;
    if (lm < 0) continue;  // uniform branch per block
    s16x8 xv = *reinterpret_cast<const s16x8*>(xe + (size_t)(m - 3 + tt) * C_ + cg);
    fx4 w0 = *(const fx4*)(cw + tt * C_ + cg);
    fx4 w1 = *(const fx4*)(cw + tt * C_ + cg + 4);
#pragma unroll
    for (int i = 0; i < 4; i++) {
      acc[i] += bits2f(xv[i]) * w0[i];
      acc[i + 4] += bits2f(xv[i + 4]) * w1[i];
    }
  }
  s16x8 o;
#pragma unroll
  for (int i = 0; i < 8; i++) o[i] = (short)f2bf(acc[i]);
  *reinterpret_cast<s16x8*>(y + (size_t)m * C_ + cg) = o;
}

extern "C" void kernel_launch(void* const* d_in, const int* in_sizes, int n_in,
                              void* d_out, int out_size, void* d_ws, size_t ws_size,
                              hipStream_t stream) {
  const float* x = (const float*)d_in[0];      // [B,L,D]
  const float* W_exp = (const float*)d_in[1];  // [D,C]
  const float* b_exp = (const float*)d_in[2];  // [C]
  const float* cw = (const float*)d_in[3];     // [K,1,C]
  const float* cb = (const float*)d_in[4];     // [C]
  const float* W_cmp = (const float*)d_in[5];  // [C,D]
  const float* b_cmp = (const float*)d_in[6];  // [D]
  float* out = (float*)d_out;                  // [B,L,D] fp32

  char* ws = (char*)d_ws;
  bfu* wexp_t = (bfu*)(ws);                                  // [C][D] bf16, 4 MiB
  bfu* wcmp_t = (bfu*)(ws + (4u << 20));                     // [D][C] bf16, 4 MiB
  bfu* xe = (bfu*)(ws + (8u << 20));                         // [M][C] bf16, 64 MiB
  bfu* y = (bfu*)(ws + (8u << 20) + (size_t)M_ * C_ * 2);    // [M][C] bf16, 64 MiB

  // 1) weight transpose+convert (B^T layout for contiguous MFMA B-fragments)
  transpose_cvt<D_, C_><<<dim3(C_ / 32, D_ / 32), dim3(32, 8), 0, stream>>>(W_exp, wexp_t);
  transpose_cvt<C_, D_><<<dim3(D_ / 32, C_ / 32), dim3(32, 8), 0, stream>>>(W_cmp, wcmp_t);
  // 2) expand GEMM: xe = x @ W_exp + b_exp   (bf16 out)
  gemm_tile<C_, D_, true, true>
      <<<dim3(M_ / 128, C_ / 128), 256, 0, stream>>>(x, wexp_t, b_exp, xe);
  // 3) depthwise causal conv: y = conv(xe) + conv_b  (bf16 out)
  dwconv_kernel<<<M_, 256, 0, stream>>>(xe, cw, cb, y);
  // 4) compress GEMM: out = y @ W_cmp + b_cmp  (fp32 out)
  gemm_tile<D_, C_, false, false>
      <<<dim3(M_ / 128, D_ / 128), 256, 0, stream>>>(y, wcmp_t, b_cmp, out);
}

// Round 2
// 232.499 us; speedup vs baseline: 1.2188x; 1.2188x over previous
//
#include <hip/hip_runtime.h>
#include <stdint.h>

#define B_ 4
#define L_ 4096
#define D_ 1024
#define C_ 2048
#define M_ (B_ * L_)  // 16384
#define LCH 16        // conv l-chunk per block

typedef __attribute__((ext_vector_type(8))) short s16x8;
typedef __attribute__((ext_vector_type(4))) float fx4;
typedef unsigned short bfu;  // bf16 bits

__device__ __forceinline__ float bits2f(short s) {
  return __uint_as_float(((uint32_t)(unsigned short)s) << 16);
}
__device__ __forceinline__ bfu f2bf(float f) {
  uint32_t u = __float_as_uint(f);
  uint32_t r = (u + 0x7FFFu + ((u >> 16) & 1u)) >> 16;  // RNE
  return (bfu)r;
}

__device__ __forceinline__ void gload_lds16(const void* g, void* l) {
  __builtin_amdgcn_global_load_lds(
      (const __attribute__((address_space(1))) void*)g,
      (__attribute__((address_space(3))) void*)l, 16, 0, 0);
}

// ---------------- fp32 -> bf16 bulk convert (vectorized, grid-stride) ----------------
__global__ __launch_bounds__(256) void cvt_f32_bf16(const float* __restrict__ in,
                                                    bfu* __restrict__ out, int n8) {
  const int stride = gridDim.x * blockDim.x;
  for (int i = blockIdx.x * blockDim.x + threadIdx.x; i < n8; i += stride) {
    const size_t off = (size_t)i * 8;
    fx4 a = *(const fx4*)(in + off);
    fx4 b = *(const fx4*)(in + off + 4);
    s16x8 o;
#pragma unroll
    for (int j = 0; j < 4; j++) {
      o[j] = (short)f2bf(a[j]);
      o[j + 4] = (short)f2bf(b[j]);
    }
    *reinterpret_cast<s16x8*>(out + off) = o;
  }
}

// ---------------- transpose + fp32->bf16 convert: out[c][r] = in[r][c] ----------------
template <int R, int CC>
__global__ __launch_bounds__(256) void transpose_cvt(const float* __restrict__ in,
                                                     bfu* __restrict__ out) {
  __shared__ float tile[32][33];
  const int bx = blockIdx.x;  // tile along CC
  const int by = blockIdx.y;  // tile along R
  const int tx = threadIdx.x;
  for (int j = threadIdx.y; j < 32; j += 8)
    tile[j][tx] = in[(size_t)(by * 32 + j) * CC + bx * 32 + tx];
  __syncthreads();
  for (int j = threadIdx.y; j < 32; j += 8)
    out[(size_t)(bx * 32 + j) * R + by * 32 + tx] = f2bf(tile[tx][j]);
}

// ---------------- 128x128 tile GEMM, BK=32, 4 waves (2x2), 16x16x32 bf16 MFMA ----------
// A: [M][KD] bf16-bits. Bt: [N][KD] bf16-bits (B transposed). C = A*B + bias.
template <int N, int KD, bool OUT_BF16>
__global__ __launch_bounds__(256) void gemm_tile(const bfu* __restrict__ A,
                                                 const bfu* __restrict__ Bt,
                                                 const float* __restrict__ bias,
                                                 void* __restrict__ Cptr) {
  __shared__ bfu sA[128 * 32];
  __shared__ bfu sB[128 * 32];
  const int t = threadIdx.x;
  const int lane = t & 63, wid = t >> 6;
  const int wr = wid >> 1, wc = wid & 1;   // 2x2 wave grid, each wave 64x64
  const int lr = lane & 15, lg = lane >> 4;
  const int row0 = blockIdx.x * 128, col0 = blockIdx.y * 128;
  const int sr = t >> 2;            // staging row 0..63 (half-tile)
  const int sk = (t & 3) * 8;       // staging k offset
  fx4 acc[4][4] = {};

  for (int k0 = 0; k0 < KD; k0 += 32) {
    gload_lds16(A + (size_t)(row0 + sr) * KD + k0 + sk, &sA[t * 8]);
    gload_lds16(A + (size_t)(row0 + 64 + sr) * KD + k0 + sk, &sA[2048 + t * 8]);
    gload_lds16(Bt + (size_t)(col0 + sr) * KD + k0 + sk, &sB[t * 8]);
    gload_lds16(Bt + (size_t)(col0 + 64 + sr) * KD + k0 + sk, &sB[2048 + t * 8]);
    __syncthreads();

    s16x8 af[4], bfr[4];
#pragma unroll
    for (int i = 0; i < 4; i++) {
      af[i] = *reinterpret_cast<const s16x8*>(&sA[(wr * 64 + i * 16 + lr) * 32 + lg * 8]);
      bfr[i] = *reinterpret_cast<const s16x8*>(&sB[(wc * 64 + i * 16 + lr) * 32 + lg * 8]);
    }
#pragma unroll
    for (int i = 0; i < 4; i++)
#pragma unroll
      for (int j = 0; j < 4; j++)
        acc[i][j] =
            __builtin_amdgcn_mfma_f32_16x16x32_bf16(af[i], bfr[j], acc[i][j], 0, 0, 0);
    __syncthreads();
  }

  // epilogue: C/D layout col=lane&15, row=(lane>>4)*4+reg  [measured m89/m91]
#pragma unroll
  for (int i = 0; i < 4; i++)
#pragma unroll
    for (int j = 0; j < 4; j++)
#pragma unroll
      for (int r = 0; r < 4; r++) {
        const int row = row0 + wr * 64 + i * 16 + lg * 4 + r;
        const int col = col0 + wc * 64 + j * 16 + lr;
        const float v = acc[i][j][r] + bias[col];
        if constexpr (OUT_BF16)
          ((bfu*)Cptr)[(size_t)row * N + col] = f2bf(v);
        else
          ((float*)Cptr)[(size_t)row * N + col] = v;
      }
}

// ---------------- depthwise causal conv K=4, sliding window, xe read ONCE --------------
// block = (batch, l-chunk of LCH rows); 256 threads x 8 channels = full C row.
__global__ __launch_bounds__(256) void dwconv_slide(const bfu* __restrict__ xe,
                                                    const float* __restrict__ cw,
                                                    const float* __restrict__ cb,
                                                    bfu* __restrict__ y) {
  const int nchunk = L_ / LCH;
  const int b = blockIdx.x / nchunk;
  const int l0 = (blockIdx.x % nchunk) * LCH;
  const int cg = threadIdx.x << 3;  // 8 channels per thread

  float w[4][8], bias8[8];
#pragma unroll
  for (int tt = 0; tt < 4; tt++) {
    fx4 w0 = *(const fx4*)(cw + tt * C_ + cg);
    fx4 w1 = *(const fx4*)(cw + tt * C_ + cg + 4);
#pragma unroll
    for (int i = 0; i < 4; i++) {
      w[tt][i] = w0[i];
      w[tt][i + 4] = w1[i];
    }
  }
  {
    fx4 c0 = *(const fx4*)(cb + cg), c1 = *(const fx4*)(cb + cg + 4);
#pragma unroll
    for (int i = 0; i < 4; i++) {
      bias8[i] = c0[i];
      bias8[i + 4] = c1[i];
    }
  }

  const size_t base = ((size_t)b * L_ + l0) * C_ + cg;
  s16x8 h0 = {}, h1 = {}, h2 = {};
  if (l0 != 0) {  // uniform per block; previous rows exist (LCH >= 3)
    h0 = *reinterpret_cast<const s16x8*>(xe + base - 3 * C_);
    h1 = *reinterpret_cast<const s16x8*>(xe + base - 2 * C_);
    h2 = *reinterpret_cast<const s16x8*>(xe + base - 1 * C_);
  }
#pragma unroll
  for (int i = 0; i < LCH; i++) {
    s16x8 h3 = *reinterpret_cast<const s16x8*>(xe + base + (size_t)i * C_);
    s16x8 o;
#pragma unroll
    for (int j = 0; j < 8; j++) {
      float v = bias8[j];
      v = fmaf(bits2f(h0[j]), w[0][j], v);
      v = fmaf(bits2f(h1[j]), w[1][j], v);
      v = fmaf(bits2f(h2[j]), w[2][j], v);
      v = fmaf(bits2f(h3[j]), w[3][j], v);
      o[j] = (short)f2bf(v);
    }
    *reinterpret_cast<s16x8*>(y + base + (size_t)i * C_) = o;
    h0 = h1;
    h1 = h2;
    h2 = h3;
  }
}

extern "C" void kernel_launch(void* const* d_in, const int* in_sizes, int n_in,
                              void* d_out, int out_size, void* d_ws, size_t ws_size,
                              hipStream_t stream) {
  const float* x = (const float*)d_in[0];      // [B,L,D]
  const float* W_exp = (const float*)d_in[1];  // [D,C]
  const float* b_exp = (const float*)d_in[2];  // [C]
  const float* cw = (const float*)d_in[3];     // [K,1,C]
  const float* cb = (const float*)d_in[4];     // [C]
  const float* W_cmp = (const float*)d_in[5];  // [C,D]
  const float* b_cmp = (const float*)d_in[6];  // [D]
  float* out = (float*)d_out;                  // [B,L,D] fp32

  char* ws = (char*)d_ws;
  bfu* wexp_t = (bfu*)(ws);                                  // [C][D] bf16, 4 MiB
  bfu* wcmp_t = (bfu*)(ws + (4u << 20));                     // [D][C] bf16, 4 MiB
  bfu* xb = (bfu*)(ws + (8u << 20));                         // [M][D] bf16, 32 MiB
  bfu* xe = (bfu*)(ws + (40u << 20));                        // [M][C] bf16, 64 MiB
  bfu* y = (bfu*)(ws + (104u << 20));                        // [M][C] bf16, 64 MiB

  // 0) x fp32 -> bf16 (done ONCE; GEMM1 then streams bf16 via global_load_lds)
  cvt_f32_bf16<<<2048, 256, 0, stream>>>(x, xb, M_ * D_ / 8);
  // 1) weight transpose+convert (B^T layout for contiguous MFMA B-fragments)
  transpose_cvt<D_, C_><<<dim3(C_ / 32, D_ / 32), dim3(32, 8), 0, stream>>>(W_exp, wexp_t);
  transpose_cvt<C_, D_><<<dim3(D_ / 32, C_ / 32), dim3(32, 8), 0, stream>>>(W_cmp, wcmp_t);
  // 2) expand GEMM: xe = x @ W_exp + b_exp   (bf16 out)
  gemm_tile<C_, D_, true>
      <<<dim3(M_ / 128, C_ / 128), 256, 0, stream>>>(xb, wexp_t, b_exp, xe);
  // 3) depthwise causal conv: y = conv(xe) + conv_b  (bf16 out, xe read once)
  dwconv_slide<<<B_ * (L_ / LCH), 256, 0, stream>>>(xe, cw, cb, y);
  // 4) compress GEMM: out = y @ W_cmp + b_cmp  (fp32 out)
  gemm_tile<D_, C_, false>
      <<<dim3(M_ / 128, D_ / 128), 256, 0, stream>>>(y, wcmp_t, b_cmp, out);
}

// Round 3
// 205.086 us; speedup vs baseline: 1.3817x; 1.1337x over previous
//
#include <hip/hip_runtime.h>
#include <stdint.h>

#define B_ 4
#define L_ 4096
#define D_ 1024
#define C_ 2048
#define M_ (B_ * L_)  // 16384
#define LCH 16        // conv l-chunk per block

typedef __attribute__((ext_vector_type(8))) short s16x8;
typedef __attribute__((ext_vector_type(4))) float fx4;
typedef unsigned short bfu;  // bf16 bits

__device__ __forceinline__ float bits2f(short s) {
  return __uint_as_float(((uint32_t)(unsigned short)s) << 16);
}
__device__ __forceinline__ bfu f2bf(float f) {
  uint32_t u = __float_as_uint(f);
  uint32_t r = (u + 0x7FFFu + ((u >> 16) & 1u)) >> 16;  // RNE
  return (bfu)r;
}

__device__ __forceinline__ void gload_lds16(const void* g, void* l) {
  __builtin_amdgcn_global_load_lds(
      (const __attribute__((address_space(1))) void*)g,
      (__attribute__((address_space(3))) void*)l, 16, 0, 0);
}

#define BAR() asm volatile("s_barrier" ::: "memory")
#define LGKM0() asm volatile("s_waitcnt lgkmcnt(0)" ::: "memory")
#define VMW4() asm volatile("s_waitcnt vmcnt(4)" ::: "memory")
#define VMW0() asm volatile("s_waitcnt vmcnt(0)" ::: "memory")

// ---------------- fp32 -> bf16 bulk convert ----------------
__global__ __launch_bounds__(256) void cvt_f32_bf16(const float* __restrict__ in,
                                                    bfu* __restrict__ out, int n8) {
  const int stride = gridDim.x * blockDim.x;
  for (int i = blockIdx.x * blockDim.x + threadIdx.x; i < n8; i += stride) {
    const size_t off = (size_t)i * 8;
    fx4 a = *(const fx4*)(in + off);
    fx4 b = *(const fx4*)(in + off + 4);
    s16x8 o;
#pragma unroll
    for (int j = 0; j < 4; j++) {
      o[j] = (short)f2bf(a[j]);
      o[j + 4] = (short)f2bf(b[j]);
    }
    *reinterpret_cast<s16x8*>(out + off) = o;
  }
}

// ---------------- transpose + fp32->bf16 convert: out[c][r] = in[r][c] ----------------
template <int R, int CC>
__global__ __launch_bounds__(256) void transpose_cvt(const float* __restrict__ in,
                                                     bfu* __restrict__ out) {
  __shared__ float tile[32][33];
  const int bx = blockIdx.x, by = blockIdx.y, tx = threadIdx.x;
  for (int j = threadIdx.y; j < 32; j += 8)
    tile[j][tx] = in[(size_t)(by * 32 + j) * CC + bx * 32 + tx];
  __syncthreads();
  for (int j = threadIdx.y; j < 32; j += 8)
    out[(size_t)(bx * 32 + j) * R + by * 32 + tx] = f2bf(tile[tx][j]);
}

// ---------------- 256x256 8-phase GEMM, BK=64, 8 waves (2Mx4N), counted vmcnt ---------
// LDS per buffer: A-kh0 [256][32], A-kh1, B-kh0, B-kh1 (16 KB each) -> 2 bufs = 128 KB.
// Swizzle (involution, both sides): byte ^= ((byte>>6)&3)<<4 within each 64B-row region.

// frag read with swizzled address
__device__ __forceinline__ s16x8 lfrag(const bfu* region, int row, int lg) {
  const int lin = row * 64 + lg * 16;          // byte offset, rows are 64 B
  const int swz = lin ^ ((lin >> 2) & 48);     // ^= ((lin>>6)&3)<<4
  return *reinterpret_cast<const s16x8*>(reinterpret_cast<const char*>(region) + swz);
}

// stage one 16 KB (matrix, k-half): 2 x global_load_lds/thread, linear LDS dest,
// pre-swizzled global source (inverse of read swizzle).
template <int KD>
__device__ __forceinline__ void stage_half(const bfu* __restrict__ Mt, int r0, int kb,
                                           bfu* region, int t) {
#pragma unroll
  for (int h = 0; h < 2; h++) {
    const int u = t + h * 512;
    const int srow = u >> 2;
    const int sslot = (u & 3) ^ (srow & 3);
    gload_lds16(Mt + (size_t)(r0 + srow) * KD + kb + sslot * 8, region + u * 8);
  }
}

template <int N, int KD, bool OUT_BF16>
__global__ __launch_bounds__(512, 2) void gemm256(const bfu* __restrict__ A,
                                                  const bfu* __restrict__ Bt,
                                                  const float* __restrict__ bias,
                                                  void* __restrict__ Cptr) {
  __shared__ bfu lds[2 * 4 * 8192];  // 128 KiB
  const int t = threadIdx.x;
  const int lane = t & 63, wid = t >> 6;
  const int wr = wid >> 2, wc = wid & 3;  // 2 (M) x 4 (N) wave grid; wave tile 128x64
  const int lr = lane & 15, lg = lane >> 4;
  // XCD-aware block swizzle (gridDim.x % 8 == 0)
  const int cpx = gridDim.x >> 3;
  const int li = (blockIdx.x & 7) * cpx + (blockIdx.x >> 3);
  const int row0 = (li % (M_ / 256)) * 256;
  const int col0 = (li / (M_ / 256)) * 256;
  constexpr int ntk = KD / 64;

  fx4 acc[8][4] = {};

  // region offsets (elements): A0=0, A1=8192, B0=16384, B1=24576; buf1 = +32768
  // prologue: t0 all 4 halves, t1 kh0 halves
  stage_half<KD>(A, row0, 0, lds + 0, t);
  stage_half<KD>(Bt, col0, 0, lds + 16384, t);
  stage_half<KD>(A, row0, 32, lds + 8192, t);
  stage_half<KD>(Bt, col0, 32, lds + 24576, t);
  stage_half<KD>(A, row0, 64, lds + 32768 + 0, t);
  stage_half<KD>(Bt, col0, 64, lds + 32768 + 16384, t);
  VMW4();  // t0's 4 halves complete; t1.kh0 (4 loads) may remain in flight
  BAR();

  for (int tau = 0; tau < ntk; ++tau) {
    bfu* cb_ = (tau & 1) ? lds + 32768 : lds;
    bfu* nb_ = (tau & 1) ? lds : lds + 32768;
    const int ar = wr * 128 + lr;
    const int br = wc * 64 + lr;
    s16x8 af[4], bf4[4];

    // ---- P1: kh0, m0-3 x n0-3 | stage (tau+1).A-kh1 -> nb_
#pragma unroll
    for (int m = 0; m < 4; m++) af[m] = lfrag(cb_ + 0, ar + m * 16, lg);
#pragma unroll
    for (int n = 0; n < 4; n++) bf4[n] = lfrag(cb_ + 16384, br + n * 16, lg);
    if (tau + 1 < ntk) stage_half<KD>(A, row0, (tau + 1) * 64 + 32, nb_ + 8192, t);
    BAR();
    LGKM0();
    __builtin_amdgcn_s_setprio(1);
#pragma unroll
    for (int m = 0; m < 4; m++)
#pragma unroll
      for (int n = 0; n < 4; n++)
        acc[m][n] = __builtin_amdgcn_mfma_f32_16x16x32_bf16(af[m], bf4[n], acc[m][n], 0, 0, 0);
    __builtin_amdgcn_s_setprio(0);
    BAR();

    // ---- P2: kh0, m4-7 (reuse B frags) | stage (tau+1).B-kh1 -> nb_
#pragma unroll
    for (int m = 0; m < 4; m++) af[m] = lfrag(cb_ + 0, ar + 64 + m * 16, lg);
    if (tau + 1 < ntk) stage_half<KD>(Bt, col0, (tau + 1) * 64 + 32, nb_ + 24576, t);
    BAR();
    LGKM0();
    __builtin_amdgcn_s_setprio(1);
#pragma unroll
    for (int m = 0; m < 4; m++)
#pragma unroll
      for (int n = 0; n < 4; n++)
        acc[m + 4][n] = __builtin_amdgcn_mfma_f32_16x16x32_bf16(af[m], bf4[n], acc[m + 4][n], 0, 0, 0);
    __builtin_amdgcn_s_setprio(0);
    BAR();

    // ---- P3: kh1, m0-3 x n0-3 | stage (tau+2).A-kh0 -> cb_ (kh0 dead after P2)
#pragma unroll
    for (int m = 0; m < 4; m++) af[m] = lfrag(cb_ + 8192, ar + m * 16, lg);
#pragma unroll
    for (int n = 0; n < 4; n++) bf4[n] = lfrag(cb_ + 24576, br + n * 16, lg);
    if (tau + 2 < ntk) stage_half<KD>(A, row0, (tau + 2) * 64, cb_ + 0, t);
    BAR();
    LGKM0();
    __builtin_amdgcn_s_setprio(1);
#pragma unroll
    for (int m = 0; m < 4; m++)
#pragma unroll
      for (int n = 0; n < 4; n++)
        acc[m][n] = __builtin_amdgcn_mfma_f32_16x16x32_bf16(af[m], bf4[n], acc[m][n], 0, 0, 0);
    __builtin_amdgcn_s_setprio(0);
    BAR();

    // ---- P4: kh1, m4-7 | stage (tau+2).B-kh0 -> cb_ | boundary counted vmcnt
#pragma unroll
    for (int m = 0; m < 4; m++) af[m] = lfrag(cb_ + 8192, ar + 64 + m * 16, lg);
    if (tau + 2 < ntk) stage_half<KD>(Bt, col0, (tau + 2) * 64, cb_ + 16384, t);
    BAR();
    LGKM0();
    __builtin_amdgcn_s_setprio(1);
#pragma unroll
    for (int m = 0; m < 4; m++)
#pragma unroll
      for (int n = 0; n < 4; n++)
        acc[m + 4][n] = __builtin_amdgcn_mfma_f32_16x16x32_bf16(af[m], bf4[n], acc[m + 4][n], 0, 0, 0);
    __builtin_amdgcn_s_setprio(0);
    if (tau < ntk - 1) {
      if (tau < ntk - 2) VMW4();  // next tile fully staged; 2 kh0 halves of tile+2 in flight
      else VMW0();                // last boundary: drain (no newer issues to count against)
    }
    BAR();
  }

  // epilogue: C/D layout col=lane&15, row=(lane>>4)*4+reg
  float bv[4];
#pragma unroll
  for (int n = 0; n < 4; n++) bv[n] = bias[col0 + wc * 64 + n * 16 + lr];
#pragma unroll
  for (int m = 0; m < 8; m++)
#pragma unroll
    for (int n = 0; n < 4; n++)
#pragma unroll
      for (int r = 0; r < 4; r++) {
        const int row = row0 + wr * 128 + m * 16 + lg * 4 + r;
        const int col = col0 + wc * 64 + n * 16 + lr;
        const float v = acc[m][n][r] + bv[n];
        if constexpr (OUT_BF16)
          ((bfu*)Cptr)[(size_t)row * N + col] = f2bf(v);
        else
          ((float*)Cptr)[(size_t)row * N + col] = v;
      }
}

// ---------------- depthwise causal conv K=4, sliding window ----------------
__global__ __launch_bounds__(256) void dwconv_slide(const bfu* __restrict__ xe,
                                                    const float* __restrict__ cw,
                                                    const float* __restrict__ cb,
                                                    bfu* __restrict__ y) {
  const int nchunk = L_ / LCH;
  const int b = blockIdx.x / nchunk;
  const int l0 = (blockIdx.x % nchunk) * LCH;
  const int cg = threadIdx.x << 3;

  float w[4][8], bias8[8];
#pragma unroll
  for (int tt = 0; tt < 4; tt++) {
    fx4 w0 = *(const fx4*)(cw + tt * C_ + cg);
    fx4 w1 = *(const fx4*)(cw + tt * C_ + cg + 4);
#pragma unroll
    for (int i = 0; i < 4; i++) {
      w[tt][i] = w0[i];
      w[tt][i + 4] = w1[i];
    }
  }
  {
    fx4 c0 = *(const fx4*)(cb + cg), c1 = *(const fx4*)(cb + cg + 4);
#pragma unroll
    for (int i = 0; i < 4; i++) {
      bias8[i] = c0[i];
      bias8[i + 4] = c1[i];
    }
  }

  const size_t base = ((size_t)b * L_ + l0) * C_ + cg;
  s16x8 h0 = {}, h1 = {}, h2 = {};
  if (l0 != 0) {
    h0 = *reinterpret_cast<const s16x8*>(xe + base - 3 * C_);
    h1 = *reinterpret_cast<const s16x8*>(xe + base - 2 * C_);
    h2 = *reinterpret_cast<const s16x8*>(xe + base - 1 * C_);
  }
#pragma unroll
  for (int i = 0; i < LCH; i++) {
    s16x8 h3 = *reinterpret_cast<const s16x8*>(xe + base + (size_t)i * C_);
    s16x8 o;
#pragma unroll
    for (int j = 0; j < 8; j++) {
      float v = bias8[j];
      v = fmaf(bits2f(h0[j]), w[0][j], v);
      v = fmaf(bits2f(h1[j]), w[1][j], v);
      v = fmaf(bits2f(h2[j]), w[2][j], v);
      v = fmaf(bits2f(h3[j]), w[3][j], v);
      o[j] = (short)f2bf(v);
    }
    *reinterpret_cast<s16x8*>(y + base + (size_t)i * C_) = o;
    h0 = h1;
    h1 = h2;
    h2 = h3;
  }
}

extern "C" void kernel_launch(void* const* d_in, const int* in_sizes, int n_in,
                              void* d_out, int out_size, void* d_ws, size_t ws_size,
                              hipStream_t stream) {
  const float* x = (const float*)d_in[0];
  const float* W_exp = (const float*)d_in[1];
  const float* b_exp = (const float*)d_in[2];
  const float* cw = (const float*)d_in[3];
  const float* cb = (const float*)d_in[4];
  const float* W_cmp = (const float*)d_in[5];
  const float* b_cmp = (const float*)d_in[6];
  float* out = (float*)d_out;

  char* ws = (char*)d_ws;
  bfu* wexp_t = (bfu*)(ws);                // [C][D] bf16, 4 MiB
  bfu* wcmp_t = (bfu*)(ws + (4u << 20));   // [D][C] bf16, 4 MiB
  bfu* xb = (bfu*)(ws + (8u << 20));       // [M][D] bf16, 32 MiB
  bfu* xe = (bfu*)(ws + (40u << 20));      // [M][C] bf16, 64 MiB
  bfu* y = (bfu*)(ws + (104u << 20));      // [M][C] bf16, 64 MiB

  cvt_f32_bf16<<<2048, 256, 0, stream>>>(x, xb, M_ * D_ / 8);
  transpose_cvt<D_, C_><<<dim3(C_ / 32, D_ / 32), dim3(32, 8), 0, stream>>>(W_exp, wexp_t);
  transpose_cvt<C_, D_><<<dim3(D_ / 32, C_ / 32), dim3(32, 8), 0, stream>>>(W_cmp, wcmp_t);
  // expand GEMM: xe = x @ W_exp + b_exp  (M x C, K=D)  grid 64*8=512
  gemm256<C_, D_, true><<<512, 512, 0, stream>>>(xb, wexp_t, b_exp, xe);
  // conv
  dwconv_slide<<<B_ * (L_ / LCH), 256, 0, stream>>>(xe, cw, cb, y);
  // compress GEMM: out = y @ W_cmp + b_cmp  (M x D, K=C)  grid 64*4=256
  gemm256<D_, C_, false><<<256, 512, 0, stream>>>(y, wcmp_t, b_cmp, out);
}

// Round 4
// 201.002 us; speedup vs baseline: 1.4098x; 1.0203x over previous
//
#include <hip/hip_runtime.h>
#include <stdint.h>

#define B_ 4
#define L_ 4096
#define D_ 1024
#define C_ 2048
#define M_ (B_ * L_)  // 16384
#define LCH 16        // conv l-chunk per block

typedef __attribute__((ext_vector_type(8))) short s16x8;
typedef __attribute__((ext_vector_type(4))) float fx4;
typedef unsigned short bfu;  // bf16 bits

__device__ __forceinline__ float bits2f(short s) {
  return __uint_as_float(((uint32_t)(unsigned short)s) << 16);
}
__device__ __forceinline__ bfu f2bf(float f) {
  uint32_t u = __float_as_uint(f);
  uint32_t r = (u + 0x7FFFu + ((u >> 16) & 1u)) >> 16;  // RNE
  return (bfu)r;
}

__device__ __forceinline__ void gload_lds16(const void* g, void* l) {
  __builtin_amdgcn_global_load_lds(
      (const __attribute__((address_space(1))) void*)g,
      (__attribute__((address_space(3))) void*)l, 16, 0, 0);
}

#define BAR() asm volatile("s_barrier" ::: "memory")
#define LGKM0() asm volatile("s_waitcnt lgkmcnt(0)" ::: "memory")
#define VMW4() asm volatile("s_waitcnt vmcnt(4)" ::: "memory")
#define VMW0() asm volatile("s_waitcnt vmcnt(0)" ::: "memory")

// ---------------- fp32 -> bf16 bulk convert ----------------
__global__ __launch_bounds__(256) void cvt_f32_bf16(const float* __restrict__ in,
                                                    bfu* __restrict__ out, int n8) {
  const int stride = gridDim.x * blockDim.x;
  for (int i = blockIdx.x * blockDim.x + threadIdx.x; i < n8; i += stride) {
    const size_t off = (size_t)i * 8;
    fx4 a = *(const fx4*)(in + off);
    fx4 b = *(const fx4*)(in + off + 4);
    s16x8 o;
#pragma unroll
    for (int j = 0; j < 4; j++) {
      o[j] = (short)f2bf(a[j]);
      o[j + 4] = (short)f2bf(b[j]);
    }
    *reinterpret_cast<s16x8*>(out + off) = o;
  }
}

// ---------------- transpose + fp32->bf16 convert: out[c][r] = in[r][c] ----------------
template <int R, int CC>
__global__ __launch_bounds__(256) void transpose_cvt(const float* __restrict__ in,
                                                     bfu* __restrict__ out) {
  __shared__ float tile[32][33];
  const int bx = blockIdx.x, by = blockIdx.y, tx = threadIdx.x;
  for (int j = threadIdx.y; j < 32; j += 8)
    tile[j][tx] = in[(size_t)(by * 32 + j) * CC + bx * 32 + tx];
  __syncthreads();
  for (int j = threadIdx.y; j < 32; j += 8)
    out[(size_t)(bx * 32 + j) * R + by * 32 + tx] = f2bf(tile[tx][j]);
}

// ---------------- 256x256 8-phase GEMM, BK=64, 8 waves (2Mx4N), counted vmcnt ---------
// LDS per buffer: A-kh0 [256][32], A-kh1, B-kh0, B-kh1 (16 KB each) -> 2 bufs = 128 KB.
// Swizzle (involution, both sides): slot' = slot ^ (row bits 1-2), i.e.
// byte ^= ((byte>>7)&3)<<4.  (Row bit 0 already picks the bank half via
// (row&1)*16; using row bits 1-2 gives 8 distinct (parity,slot') combos per
// 16-row lg-group -> 2 lanes/bank = free. R3's (row&0-1) variant was 4-way.)

__device__ __forceinline__ s16x8 lfrag(const bfu* region, int row, int lg) {
  const int lin = row * 64 + lg * 16;          // byte offset, rows are 64 B
  const int swz = lin ^ ((lin >> 3) & 48);     // ^= ((row>>1)&3)<<4
  return *reinterpret_cast<const s16x8*>(reinterpret_cast<const char*>(region) + swz);
}

// stage one 16 KB (matrix, k-half): 2 x global_load_lds/thread, linear LDS dest,
// pre-swizzled global source (inverse of read swizzle).
template <int KD>
__device__ __forceinline__ void stage_half(const bfu* __restrict__ Mt, int r0, int kb,
                                           bfu* region, int t) {
#pragma unroll
  for (int h = 0; h < 2; h++) {
    const int u = t + h * 512;
    const int srow = u >> 2;
    const int sslot = (u & 3) ^ ((srow >> 1) & 3);
    gload_lds16(Mt + (size_t)(r0 + srow) * KD + kb + sslot * 8, region + u * 8);
  }
}

template <int N, int KD, bool OUT_BF16>
__global__ __launch_bounds__(512, 2) void gemm256(const bfu* __restrict__ A,
                                                  const bfu* __restrict__ Bt,
                                                  const float* __restrict__ bias,
                                                  void* __restrict__ Cptr) {
  __shared__ bfu lds[2 * 4 * 8192];  // 128 KiB
  const int t = threadIdx.x;
  const int lane = t & 63, wid = t >> 6;
  const int wr = wid >> 2, wc = wid & 3;  // 2 (M) x 4 (N) wave grid; wave tile 128x64
  const int lr = lane & 15, lg = lane >> 4;
  // XCD-aware block swizzle (gridDim.x % 8 == 0)
  const int cpx = gridDim.x >> 3;
  const int li = (blockIdx.x & 7) * cpx + (blockIdx.x >> 3);
  const int row0 = (li % (M_ / 256)) * 256;
  const int col0 = (li / (M_ / 256)) * 256;
  constexpr int ntk = KD / 64;

  fx4 acc[8][4] = {};

  // region offsets (elements): A0=0, A1=8192, B0=16384, B1=24576; buf1 = +32768
  stage_half<KD>(A, row0, 0, lds + 0, t);
  stage_half<KD>(Bt, col0, 0, lds + 16384, t);
  stage_half<KD>(A, row0, 32, lds + 8192, t);
  stage_half<KD>(Bt, col0, 32, lds + 24576, t);
  stage_half<KD>(A, row0, 64, lds + 32768 + 0, t);
  stage_half<KD>(Bt, col0, 64, lds + 32768 + 16384, t);
  VMW4();  // t0's 4 halves complete; t1.kh0 (4 loads) may remain in flight
  BAR();

  for (int tau = 0; tau < ntk; ++tau) {
    bfu* cb_ = (tau & 1) ? lds + 32768 : lds;
    bfu* nb_ = (tau & 1) ? lds : lds + 32768;
    const int ar = wr * 128 + lr;
    const int br = wc * 64 + lr;
    s16x8 af[4], bf4[4];

    // ---- P1: kh0, m0-3 x n0-3 | stage (tau+1).A-kh1 -> nb_
#pragma unroll
    for (int m = 0; m < 4; m++) af[m] = lfrag(cb_ + 0, ar + m * 16, lg);
#pragma unroll
    for (int n = 0; n < 4; n++) bf4[n] = lfrag(cb_ + 16384, br + n * 16, lg);
    if (tau + 1 < ntk) stage_half<KD>(A, row0, (tau + 1) * 64 + 32, nb_ + 8192, t);
    BAR();
    LGKM0();
    __builtin_amdgcn_s_setprio(1);
#pragma unroll
    for (int m = 0; m < 4; m++)
#pragma unroll
      for (int n = 0; n < 4; n++)
        acc[m][n] = __builtin_amdgcn_mfma_f32_16x16x32_bf16(af[m], bf4[n], acc[m][n], 0, 0, 0);
    __builtin_amdgcn_s_setprio(0);
    BAR();

    // ---- P2: kh0, m4-7 (reuse B frags) | stage (tau+1).B-kh1 -> nb_
#pragma unroll
    for (int m = 0; m < 4; m++) af[m] = lfrag(cb_ + 0, ar + 64 + m * 16, lg);
    if (tau + 1 < ntk) stage_half<KD>(Bt, col0, (tau + 1) * 64 + 32, nb_ + 24576, t);
    BAR();
    LGKM0();
    __builtin_amdgcn_s_setprio(1);
#pragma unroll
    for (int m = 0; m < 4; m++)
#pragma unroll
      for (int n = 0; n < 4; n++)
        acc[m + 4][n] = __builtin_amdgcn_mfma_f32_16x16x32_bf16(af[m], bf4[n], acc[m + 4][n], 0, 0, 0);
    __builtin_amdgcn_s_setprio(0);
    BAR();

    // ---- P3: kh1, m0-3 x n0-3 | stage (tau+2).A-kh0 -> cb_ (kh0 dead after P2)
#pragma unroll
    for (int m = 0; m < 4; m++) af[m] = lfrag(cb_ + 8192, ar + m * 16, lg);
#pragma unroll
    for (int n = 0; n < 4; n++) bf4[n] = lfrag(cb_ + 24576, br + n * 16, lg);
    if (tau + 2 < ntk) stage_half<KD>(A, row0, (tau + 2) * 64, cb_ + 0, t);
    BAR();
    LGKM0();
    __builtin_amdgcn_s_setprio(1);
#pragma unroll
    for (int m = 0; m < 4; m++)
#pragma unroll
      for (int n = 0; n < 4; n++)
        acc[m][n] = __builtin_amdgcn_mfma_f32_16x16x32_bf16(af[m], bf4[n], acc[m][n], 0, 0, 0);
    __builtin_amdgcn_s_setprio(0);
    BAR();

    // ---- P4: kh1, m4-7 | stage (tau+2).B-kh0 -> cb_ | boundary counted vmcnt
#pragma unroll
    for (int m = 0; m < 4; m++) af[m] = lfrag(cb_ + 8192, ar + 64 + m * 16, lg);
    if (tau + 2 < ntk) stage_half<KD>(Bt, col0, (tau + 2) * 64, cb_ + 16384, t);
    BAR();
    LGKM0();
    __builtin_amdgcn_s_setprio(1);
#pragma unroll
    for (int m = 0; m < 4; m++)
#pragma unroll
      for (int n = 0; n < 4; n++)
        acc[m + 4][n] = __builtin_amdgcn_mfma_f32_16x16x32_bf16(af[m], bf4[n], acc[m + 4][n], 0, 0, 0);
    __builtin_amdgcn_s_setprio(0);
    if (tau < ntk - 1) {
      if (tau < ntk - 2) VMW4();  // next tile fully staged; 2 kh0 halves of tile+2 in flight
      else VMW0();                // last boundary: drain
    }
    BAR();
  }

  // epilogue: C/D layout col=lane&15, row=(lane>>4)*4+reg
  float bv[4];
#pragma unroll
  for (int n = 0; n < 4; n++) bv[n] = bias[col0 + wc * 64 + n * 16 + lr];
#pragma unroll
  for (int m = 0; m < 8; m++)
#pragma unroll
    for (int n = 0; n < 4; n++)
#pragma unroll
      for (int r = 0; r < 4; r++) {
        const int row = row0 + wr * 128 + m * 16 + lg * 4 + r;
        const int col = col0 + wc * 64 + n * 16 + lr;
        const float v = acc[m][n][r] + bv[n];
        if constexpr (OUT_BF16)
          ((bfu*)Cptr)[(size_t)row * N + col] = f2bf(v);
        else
          ((float*)Cptr)[(size_t)row * N + col] = v;
      }
}

// ---------------- depthwise causal conv K=4, sliding window ----------------
__global__ __launch_bounds__(256) void dwconv_slide(const bfu* __restrict__ xe,
                                                    const float* __restrict__ cw,
                                                    const float* __restrict__ cb,
                                                    bfu* __restrict__ y) {
  const int nchunk = L_ / LCH;
  const int b = blockIdx.x / nchunk;
  const int l0 = (blockIdx.x % nchunk) * LCH;
  const int cg = threadIdx.x << 3;

  float w[4][8], bias8[8];
#pragma unroll
  for (int tt = 0; tt < 4; tt++) {
    fx4 w0 = *(const fx4*)(cw + tt * C_ + cg);
    fx4 w1 = *(const fx4*)(cw + tt * C_ + cg + 4);
#pragma unroll
    for (int i = 0; i < 4; i++) {
      w[tt][i] = w0[i];
      w[tt][i + 4] = w1[i];
    }
  }
  {
    fx4 c0 = *(const fx4*)(cb + cg), c1 = *(const fx4*)(cb + cg + 4);
#pragma unroll
    for (int i = 0; i < 4; i++) {
      bias8[i] = c0[i];
      bias8[i + 4] = c1[i];
    }
  }

  const size_t base = ((size_t)b * L_ + l0) * C_ + cg;
  s16x8 h0 = {}, h1 = {}, h2 = {};
  if (l0 != 0) {
    h0 = *reinterpret_cast<const s16x8*>(xe + base - 3 * C_);
    h1 = *reinterpret_cast<const s16x8*>(xe + base - 2 * C_);
    h2 = *reinterpret_cast<const s16x8*>(xe + base - 1 * C_);
  }
#pragma unroll
  for (int i = 0; i < LCH; i++) {
    s16x8 h3 = *reinterpret_cast<const s16x8*>(xe + base + (size_t)i * C_);
    s16x8 o;
#pragma unroll
    for (int j = 0; j < 8; j++) {
      float v = bias8[j];
      v = fmaf(bits2f(h0[j]), w[0][j], v);
      v = fmaf(bits2f(h1[j]), w[1][j], v);
      v = fmaf(bits2f(h2[j]), w[2][j], v);
      v = fmaf(bits2f(h3[j]), w[3][j], v);
      o[j] = (short)f2bf(v);
    }
    *reinterpret_cast<s16x8*>(y + base + (size_t)i * C_) = o;
    h0 = h1;
    h1 = h2;
    h2 = h3;
  }
}

extern "C" void kernel_launch(void* const* d_in, const int* in_sizes, int n_in,
                              void* d_out, int out_size, void* d_ws, size_t ws_size,
                              hipStream_t stream) {
  const float* x = (const float*)d_in[0];
  const float* W_exp = (const float*)d_in[1];
  const float* b_exp = (const float*)d_in[2];
  const float* cw = (const float*)d_in[3];
  const float* cb = (const float*)d_in[4];
  const float* W_cmp = (const float*)d_in[5];
  const float* b_cmp = (const float*)d_in[6];
  float* out = (float*)d_out;

  char* ws = (char*)d_ws;
  bfu* wexp_t = (bfu*)(ws);                // [C][D] bf16, 4 MiB
  bfu* wcmp_t = (bfu*)(ws + (4u << 20));   // [D][C] bf16, 4 MiB
  bfu* xb = (bfu*)(ws + (8u << 20));       // [M][D] bf16, 32 MiB
  bfu* xe = (bfu*)(ws + (40u << 20));      // [M][C] bf16, 64 MiB
  bfu* y = (bfu*)(ws + (104u << 20));      // [M][C] bf16, 64 MiB

  cvt_f32_bf16<<<2048, 256, 0, stream>>>(x, xb, M_ * D_ / 8);
  transpose_cvt<D_, C_><<<dim3(C_ / 32, D_ / 32), dim3(32, 8), 0, stream>>>(W_exp, wexp_t);
  transpose_cvt<C_, D_><<<dim3(D_ / 32, C_ / 32), dim3(32, 8), 0, stream>>>(W_cmp, wcmp_t);
  // expand GEMM: xe = x @ W_exp + b_exp  (M x C, K=D)  grid 64*8=512
  gemm256<C_, D_, true><<<512, 512, 0, stream>>>(xb, wexp_t, b_exp, xe);
  // conv
  dwconv_slide<<<B_ * (L_ / LCH), 256, 0, stream>>>(xe, cw, cb, y);
  // compress GEMM: out = y @ W_cmp + b_cmp  (M x D, K=C)  grid 64*4=256
  gemm256<D_, C_, false><<<256, 512, 0, stream>>>(y, wcmp_t, b_cmp, out);
}